// Round 3
// baseline (531.077 us; speedup 1.0000x reference)
//
#include <hip/hip_runtime.h>
#include <hip/hip_bf16.h>

#define N_NODES 50000
#define N_EDGES 800000
#define HEADS   4
#define NEG_SLOPE 0.2f

template <typename T> __device__ __forceinline__ float cvt(T v);
template <> __device__ __forceinline__ float cvt<float>(float v) { return v; }
template <> __device__ __forceinline__ float cvt<__hip_bfloat16>(__hip_bfloat16 v) {
    return __bfloat162float(v);
}

// ---------------- runtime dtype probes (host can't sync under graph capture) -
// flags[0]: edge_index is int64 (odd int32 words of node ids < 50000 are all 0;
//           for int32 layout P(32 random ids all zero) ~ (1/50000)^32 ~ 0).
// flags[1]: x is fp32. For bf16-packed words the LOW 16 bits are a sane N(0,1)
//           bf16 (exp in [90,141], p~1); for fp32 words they're mantissa junk
//           (p~0.2). 64 samples, cut at 32: misclassification ~1e-9.
__global__ void k_detect(const unsigned* __restrict__ xw, const int* __restrict__ ei,
                         int* __restrict__ flags) {
    if (blockIdx.x == 0 && threadIdx.x == 0) {
        int all0 = 1;
        for (int i = 1; i < 64; i += 2) all0 &= (ei[i] == 0);
        flags[0] = all0;
        int sane = 0;
        for (int i = 0; i < 64; ++i) {
            unsigned e = (xw[i] >> 7) & 0xFF;   // exponent of low half as bf16
            sane += (e >= 90 && e <= 141);
        }
        flags[1] = (sane < 32);
    }
}

// ---------------- init workspace (ws is poisoned 0xAA before every launch) ---
__global__ __launch_bounds__(256) void k_init(float* __restrict__ m,
                                              float* __restrict__ s,
                                              float* __restrict__ acc) {
    int i = blockIdx.x * blockDim.x + threadIdx.x;
    if (i < N_NODES * 64) acc[i] = 0.0f;
    if (i < N_NODES * HEADS) { m[i] = -INFINITY; s[i] = 0.0f; }
}

// ---------------- xt = x @ W, plus a_src/a_dst head dots ---------------------
// one block (256 thr) per node; thread c computes xt[n, c]; wave w == head w.
template <typename T>
__device__ __forceinline__ void transform_body(
    const T* __restrict__ x, const T* __restrict__ W,
    const T* __restrict__ att_src, const T* __restrict__ att_dst,
    float* __restrict__ xt, float* __restrict__ a_src, float* __restrict__ a_dst) {
    __shared__ float xs[64];
    const int n = blockIdx.x;
    const int c = threadIdx.x;
    if (c < 64) xs[c] = cvt<T>(x[n * 64 + c]);
    __syncthreads();
    float acc = 0.0f;
#pragma unroll
    for (int k = 0; k < 64; ++k)
        acc += xs[k] * cvt<T>(W[k * 256 + c]);   // coalesced 256-wide rows; W L1-resident
    xt[(size_t)n * 256 + c] = acc;

    float ps = acc * cvt<T>(att_src[c]);   // att_* is [H,C] flat == index c
    float pd = acc * cvt<T>(att_dst[c]);
#pragma unroll
    for (int off = 32; off > 0; off >>= 1) {
        ps += __shfl_down(ps, off, 64);
        pd += __shfl_down(pd, off, 64);
    }
    if ((c & 63) == 0) {
        int h = c >> 6;
        a_src[n * HEADS + h] = ps;
        a_dst[n * HEADS + h] = pd;
    }
}

__global__ __launch_bounds__(256) void k_transform(
    const void* __restrict__ x, const void* __restrict__ W,
    const void* __restrict__ att_src, const void* __restrict__ att_dst,
    const int* __restrict__ flags,
    float* __restrict__ xt, float* __restrict__ a_src, float* __restrict__ a_dst) {
    if (flags[1])
        transform_body<float>((const float*)x, (const float*)W,
                              (const float*)att_src, (const float*)att_dst,
                              xt, a_src, a_dst);
    else
        transform_body<__hip_bfloat16>((const __hip_bfloat16*)x, (const __hip_bfloat16*)W,
                                       (const __hip_bfloat16*)att_src,
                                       (const __hip_bfloat16*)att_dst,
                                       xt, a_src, a_dst);
}

__device__ __forceinline__ void edge_endpoints(const int* __restrict__ ei, int t, int f64,
                                               int& src, int& dst) {
    if (t < N_EDGES) {
        if (f64) { src = ei[2 * t]; dst = ei[2 * N_EDGES + 2 * t]; }   // int64 low words
        else     { src = ei[t];     dst = ei[N_EDGES + t]; }           // int32 layout
    } else { src = t - N_EDGES; dst = src; }                           // appended self loops
}

// ---------------- segment max over dst (thread per edge,head) ----------------
__global__ __launch_bounds__(256) void k_max(const int* __restrict__ ei,
                                             const int* __restrict__ flags,
                                             const float* __restrict__ a_src,
                                             const float* __restrict__ a_dst,
                                             float* __restrict__ m) {
    int idx = blockIdx.x * blockDim.x + threadIdx.x;
    if (idx >= (N_EDGES + N_NODES) * HEADS) return;
    int f64 = flags[0];
    int t = idx >> 2, h = idx & 3;
    int src, dst; edge_endpoints(ei, t, f64, src, dst);
    float e = a_src[src * HEADS + h] + a_dst[dst * HEADS + h];
    e = e > 0.0f ? e : NEG_SLOPE * e;
    float* addr = m + dst * HEADS + h;
    if (e >= 0.0f) atomicMax((int*)addr, __float_as_int(e));
    else           atomicMin((unsigned int*)addr, __float_as_uint(e));
}

// ---------------- segment sum of exp(e - m) ----------------------------------
__global__ __launch_bounds__(256) void k_sum(const int* __restrict__ ei,
                                             const int* __restrict__ flags,
                                             const float* __restrict__ a_src,
                                             const float* __restrict__ a_dst,
                                             const float* __restrict__ m,
                                             float* __restrict__ s) {
    int idx = blockIdx.x * blockDim.x + threadIdx.x;
    if (idx >= (N_EDGES + N_NODES) * HEADS) return;
    int f64 = flags[0];
    int t = idx >> 2, h = idx & 3;
    int src, dst; edge_endpoints(ei, t, f64, src, dst);
    float e = a_src[src * HEADS + h] + a_dst[dst * HEADS + h];
    e = e > 0.0f ? e : NEG_SLOPE * e;
    atomicAdd(s + dst * HEADS + h, expf(e - m[dst * HEADS + h]));
}

// ---------------- weighted scatter-aggregate, head-sum fused -----------------
// one wave (64 lanes) per edge; lane = channel; head loop in-register, so
// atomic traffic is 64 floats/edge instead of 256.
__global__ __launch_bounds__(256) void k_aggregate(
    const int* __restrict__ ei, const int* __restrict__ flags,
    const float* __restrict__ a_src, const float* __restrict__ a_dst,
    const float* __restrict__ m, const float* __restrict__ s,
    const float* __restrict__ xt, float* __restrict__ acc) {
    int gid = blockIdx.x * blockDim.x + threadIdx.x;
    int t = gid >> 6;
    int lane = threadIdx.x & 63;
    if (t >= N_EDGES + N_NODES) return;
    int f64 = flags[0];
    int src, dst; edge_endpoints(ei, t, f64, src, dst);
    float v = 0.0f;
#pragma unroll
    for (int h = 0; h < HEADS; ++h) {
        float e = a_src[src * HEADS + h] + a_dst[dst * HEADS + h];  // broadcast loads
        e = e > 0.0f ? e : NEG_SLOPE * e;
        float alpha = expf(e - m[dst * HEADS + h]) / s[dst * HEADS + h];
        v += alpha * xt[(size_t)src * 256 + h * 64 + lane];
    }
    atomicAdd(acc + (size_t)dst * 64 + lane, v);
}

// ---------------- mean heads + bias, relu, fc → fp32 scores ------------------
template <typename T>
__device__ __forceinline__ void final_body(const float* __restrict__ acc,
                                           const T* __restrict__ bias,
                                           const T* __restrict__ fc_w,
                                           const T* __restrict__ fc_b,
                                           float* __restrict__ out) {
    int gid = blockIdx.x * blockDim.x + threadIdx.x;
    int n = gid >> 6;
    int lane = threadIdx.x & 63;
    if (n >= N_NODES) return;
    float v = acc[(size_t)n * 64 + lane] * (1.0f / HEADS) + cvt<T>(bias[lane]);
    v = v > 0.0f ? v : 0.0f;          // relu
    v *= cvt<T>(fc_w[lane]);          // fc_w is [64,1]
#pragma unroll
    for (int off = 32; off > 0; off >>= 1) v += __shfl_down(v, off, 64);
    if (lane == 0) out[n] = v + cvt<T>(fc_b[0]);   // fp32 output (reference dtype)
}

__global__ __launch_bounds__(256) void k_final(const float* __restrict__ acc,
                                               const void* __restrict__ bias,
                                               const void* __restrict__ fc_w,
                                               const void* __restrict__ fc_b,
                                               const int* __restrict__ flags,
                                               float* __restrict__ out) {
    if (flags[1])
        final_body<float>(acc, (const float*)bias, (const float*)fc_w,
                          (const float*)fc_b, out);
    else
        final_body<__hip_bfloat16>(acc, (const __hip_bfloat16*)bias,
                                   (const __hip_bfloat16*)fc_w,
                                   (const __hip_bfloat16*)fc_b, out);
}

extern "C" void kernel_launch(void* const* d_in, const int* in_sizes, int n_in,
                              void* d_out, int out_size, void* d_ws, size_t ws_size,
                              hipStream_t stream) {
    const void* x       = d_in[0];
    const int*  ei      = (const int*)d_in[1];
    const void* W       = d_in[2];
    const void* att_src = d_in[3];
    const void* att_dst = d_in[4];
    const void* bias    = d_in[5];
    const void* fc_w    = d_in[6];
    const void* fc_b    = d_in[7];
    float* out = (float*)d_out;

    float* ws    = (float*)d_ws;
    float* xt    = ws;                              // N*256 fp32  (51.2 MB)
    float* a_src = xt + (size_t)N_NODES * 256;      // N*4
    float* a_dst = a_src + N_NODES * HEADS;         // N*4
    float* m     = a_dst + N_NODES * HEADS;         // N*4
    float* s     = m + N_NODES * HEADS;             // N*4
    float* acc   = s + N_NODES * HEADS;             // N*64  (12.8 MB)
    int*   flags = (int*)(acc + (size_t)N_NODES * 64);

    const int EH = (N_EDGES + N_NODES) * HEADS;     // 3,400,000

    k_detect<<<1, 64, 0, stream>>>((const unsigned*)x, ei, flags);
    k_init<<<(N_NODES * 64 + 255) / 256, 256, 0, stream>>>(m, s, acc);
    k_transform<<<N_NODES, 256, 0, stream>>>(x, W, att_src, att_dst, flags,
                                             xt, a_src, a_dst);
    k_max<<<(EH + 255) / 256, 256, 0, stream>>>(ei, flags, a_src, a_dst, m);
    k_sum<<<(EH + 255) / 256, 256, 0, stream>>>(ei, flags, a_src, a_dst, m, s);
    k_aggregate<<<((N_EDGES + N_NODES) * 64 + 255) / 256, 256, 0, stream>>>(
        ei, flags, a_src, a_dst, m, s, xt, acc);
    k_final<<<(N_NODES * 64 + 255) / 256, 256, 0, stream>>>(acc, bias, fc_w, fc_b,
                                                            flags, out);
}